// Round 4
// baseline (440.879 us; speedup 1.0000x reference)
//
#include <hip/hip_runtime.h>
#include <hip/hip_cooperative_groups.h>

namespace cg = cooperative_groups;

#define Bn 8
#define Tn 1024
#define Fn 128
#define Hn 64
#define NC 64      // chunks per batch
#define CSZ 16     // tokens per chunk (== tokens per block)

constexpr float EPS = 1e-5f;

__device__ __forceinline__ void fma4(float4& a, float s, const float4& w) {
    a.x = fmaf(s, w.x, a.x); a.y = fmaf(s, w.y, a.y);
    a.z = fmaf(s, w.z, a.z); a.w = fmaf(s, w.w, a.w);
}
__device__ __forceinline__ float4 f4zero() { return make_float4(0.f, 0.f, 0.f, 0.f); }

struct SharedA {               // phase A GEMM staging (dead after phase A)
    float LW[32 * 260];        // [k in chunk][out 0..255]
    float LX[128 * 20];        // [k][token 0..15], pitch 20 (80 B, 16B-aligned rows)
};
struct SharedC {               // phase C FFN (staged at end of phase A)
    float WT[2][64 * 68];      // transposed [k][h], pitch 68 (272 B, 16B-aligned)
    float Yl[CSZ * 68];
    float Y2[CSZ * 68];
    float Lb[2][64];
};
struct Shared {
    float Kc[CSZ * Hn];        // persists A -> C
    float Qc[CSZ * Hn];
    float Vc[CSZ * Hn];
    float Rc[CSZ * Hn];
    union { SharedA a; SharedC c; } u;
    float seg[4][64];          // phase B cross-wave segment sums
};
// total: (4*1024 + 11008 + 256) * 4 B = 61440 B = 60 KB -> 2 blocks/CU

__global__ __launch_bounds__(256, 2) void fwp_fused(
    const float* __restrict__ x, const float* __restrict__ state,
    const float* __restrict__ Wk, const float* __restrict__ Wq, const float* __restrict__ Wv,
    const float* __restrict__ gamma, const float* __restrict__ beta,
    const float* __restrict__ W1, const float* __restrict__ b1,
    const float* __restrict__ W2, const float* __restrict__ b2,
    const float* __restrict__ Wsp, const float* __restrict__ bs,
    float* __restrict__ csum, float* __restrict__ outY, float* __restrict__ outS) {
    __shared__ Shared sh;
    cg::grid_group grid = cg::this_grid();
    const int tid = threadIdx.x;
    const int bl  = blockIdx.x;
    const int b   = bl >> 6, c = bl & 63;
    const int t0  = c * CSZ;

    // ================= Phase A: LN + projections + chunk kv-sum =================
    // LN: token tt = tid>>4, 16 lanes/token each owning 8 feature cols
    {
        const int tt = tid >> 4, ffq = tid & 15;
        const float* xp = x + (size_t)(b * Tn + t0 + tt) * Fn + ffq * 8;
        const float4 xr0 = *(const float4*)(xp);
        const float4 xr1 = *(const float4*)(xp + 4);
        float s  = xr0.x + xr0.y + xr0.z + xr0.w + xr1.x + xr1.y + xr1.z + xr1.w;
        float ss = xr0.x * xr0.x + xr0.y * xr0.y + xr0.z * xr0.z + xr0.w * xr0.w
                 + xr1.x * xr1.x + xr1.y * xr1.y + xr1.z * xr1.z + xr1.w * xr1.w;
#pragma unroll
        for (int m = 1; m < 16; m <<= 1) { s += __shfl_xor(s, m); ss += __shfl_xor(ss, m); }
        const float mu = s * (1.f / Fn);
        const float rs = rsqrtf(ss * (1.f / Fn) - mu * mu + EPS);
        const float4 g0 = *(const float4*)(gamma + ffq * 8);
        const float4 g1 = *(const float4*)(gamma + ffq * 8 + 4);
        const float4 be0 = *(const float4*)(beta + ffq * 8);
        const float4 be1 = *(const float4*)(beta + ffq * 8 + 4);
        float* LX = sh.u.a.LX;
        LX[(ffq * 8 + 0) * 20 + tt] = (xr0.x - mu) * rs * g0.x + be0.x;
        LX[(ffq * 8 + 1) * 20 + tt] = (xr0.y - mu) * rs * g0.y + be0.y;
        LX[(ffq * 8 + 2) * 20 + tt] = (xr0.z - mu) * rs * g0.z + be0.z;
        LX[(ffq * 8 + 3) * 20 + tt] = (xr0.w - mu) * rs * g0.w + be0.w;
        LX[(ffq * 8 + 4) * 20 + tt] = (xr1.x - mu) * rs * g1.x + be1.x;
        LX[(ffq * 8 + 5) * 20 + tt] = (xr1.y - mu) * rs * g1.y + be1.y;
        LX[(ffq * 8 + 6) * 20 + tt] = (xr1.z - mu) * rs * g1.z + be1.z;
        LX[(ffq * 8 + 7) * 20 + tt] = (xr1.w - mu) * rs * g1.w + be1.w;
    }
    // GEMM [16 x 128] @ [128 x 256]: wave w stages matrix w; thread = (tg: 4 tokens, cgq: 4 outs)
    const int wave = tid >> 6;
    const int cgq  = tid & 63;
    const int tg   = wave;
    const float* WmS  = (wave == 0) ? Wk : (wave == 1) ? Wq : (wave == 2) ? Wv : Wsp;
    const float* wrow = WmS + (tid & 63) * Fn;
    float4 acc[4];
#pragma unroll
    for (int i = 0; i < 4; i++) acc[i] = f4zero();
    for (int kc0 = 0; kc0 < Fn; kc0 += 32) {
#pragma unroll
        for (int r = 0; r < 8; r++) {
            const float4 wv = *(const float4*)(wrow + kc0 + r * 4);
            sh.u.a.LW[(r * 4 + 0) * 260 + tid] = wv.x;
            sh.u.a.LW[(r * 4 + 1) * 260 + tid] = wv.y;
            sh.u.a.LW[(r * 4 + 2) * 260 + tid] = wv.z;
            sh.u.a.LW[(r * 4 + 3) * 260 + tid] = wv.w;
        }
        __syncthreads();
#pragma unroll 8
        for (int kc = 0; kc < 32; kc++) {
            const float4 w4 = *(const float4*)&sh.u.a.LW[kc * 260 + cgq * 4];
            const float4 xa = *(const float4*)&sh.u.a.LX[(kc0 + kc) * 20 + tg * 4];
            fma4(acc[0], xa.x, w4); fma4(acc[1], xa.y, w4);
            fma4(acc[2], xa.z, w4); fma4(acc[3], xa.w, w4);
        }
        __syncthreads();
    }
    // epilogue: relu (K,Q), sum-norm (K,Q), +bs (R); write to LDS K/Q/V/R
    {
        const int m  = cgq >> 4;
        const int h0 = (cgq & 15) * 4;
        if (m < 2) {
#pragma unroll
            for (int i = 0; i < 4; i++) {
                acc[i].x = fmaxf(acc[i].x, 0.f); acc[i].y = fmaxf(acc[i].y, 0.f);
                acc[i].z = fmaxf(acc[i].z, 0.f); acc[i].w = fmaxf(acc[i].w, 0.f);
            }
        }
        float rsum[4];
#pragma unroll
        for (int i = 0; i < 4; i++) {
            rsum[i] = acc[i].x + acc[i].y + acc[i].z + acc[i].w;
            rsum[i] += __shfl_xor(rsum[i], 1);
            rsum[i] += __shfl_xor(rsum[i], 2);
            rsum[i] += __shfl_xor(rsum[i], 4);
            rsum[i] += __shfl_xor(rsum[i], 8);
        }
        if (m < 2) {
#pragma unroll
            for (int i = 0; i < 4; i++) {
                const float inv = 1.f / (EPS + rsum[i]);
                acc[i].x *= inv; acc[i].y *= inv; acc[i].z *= inv; acc[i].w *= inv;
            }
        } else if (m == 3) {
            const float4 bv = *(const float4*)(bs + h0);
#pragma unroll
            for (int i = 0; i < 4; i++) {
                acc[i].x += bv.x; acc[i].y += bv.y; acc[i].z += bv.z; acc[i].w += bv.w;
            }
        }
        float* dst = (m == 0) ? sh.Kc : (m == 1) ? sh.Qc : (m == 2) ? sh.Vc : sh.Rc;
#pragma unroll
        for (int ti = 0; ti < 4; ti++)
            *(float4*)(dst + (tg * 4 + ti) * Hn + h0) = acc[ti];
    }
    // stage FFN weights into the (now dead) LW/LX region
#pragma unroll
    for (int mat = 0; mat < 2; mat++) {
        const float4* Wg = (const float4*)(mat ? W2 : W1);
#pragma unroll
        for (int r = 0; r < 4; r++) {
            const int f4i = tid + 256 * r;
            const float4 wv = Wg[f4i];
            const int h = f4i >> 4;
            const int k = (f4i & 15) * 4;
            sh.u.c.WT[mat][(k + 0) * 68 + h] = wv.x;
            sh.u.c.WT[mat][(k + 1) * 68 + h] = wv.y;
            sh.u.c.WT[mat][(k + 2) * 68 + h] = wv.z;
            sh.u.c.WT[mat][(k + 3) * 68 + h] = wv.w;
        }
    }
    if (tid < 64) sh.u.c.Lb[0][tid] = b1[tid];
    else if (tid < 128) sh.u.c.Lb[1][tid - 64] = b2[tid - 64];
    __syncthreads();
    // chunk kv-sum -> csum
    const int jq = tid & 15, rr = tid >> 4;
    {
        float4 a4[4];
#pragma unroll
        for (int sI = 0; sI < 4; sI++) a4[sI] = f4zero();
        for (int t = 0; t < CSZ; t++) {
            const float4 kv = ((const float4*)sh.Kc)[t * 16 + jq];
#pragma unroll
            for (int sI = 0; sI < 4; sI++) fma4(a4[sI], sh.Vc[t * Hn + sI * 16 + rr], kv);
        }
        float4* out0 = (float4*)(csum + (size_t)bl * 4096);
#pragma unroll
        for (int sI = 0; sI < 4; sI++) out0[sI * 256 + tid] = a4[sI];
    }
    __threadfence();
    grid.sync();

    // ================= Phase B: in-place exclusive chunk scan =================
    // block = (b2, eg): 64 e-lanes; wave w owns chunks w*16 .. w*16+15
    {
        const int b2 = bl >> 6, eg = bl & 63;
        const int el = tid & 63, w = tid >> 6;
        const int e  = eg * 64 + el;
        float* cbase = csum + (size_t)b2 * (NC * 4096) + e;
        float v[16];
        float segs = 0.f;
#pragma unroll
        for (int i = 0; i < 16; i++) {
            v[i] = cbase[(size_t)(w * 16 + i) * 4096];
            segs += v[i];
        }
        sh.seg[w][el] = segs;
        __syncthreads();
        float base = state[b2 * 4096 + e];
        for (int w2 = 0; w2 < w; w2++) base += sh.seg[w2][el];
#pragma unroll
        for (int i = 0; i < 16; i++) {
            cbase[(size_t)(w * 16 + i) * 4096] = base;   // exclusive prefix
            base += v[i];
        }
    }
    __threadfence();
    grid.sync();

    // ================= Phase C: replay chunk, stream S, y + FFN + residual =================
    float4 S4[4];
    {
        const float4* cs = (const float4*)(csum + (size_t)bl * 4096);
#pragma unroll
        for (int sI = 0; sI < 4; sI++) S4[sI] = cs[sI * 256 + tid];
    }
    float4* SBase = (float4*)outS + (size_t)(b * Tn + t0) * 1024;
    for (int t = 0; t < CSZ; t++) {
        const float4 kv = ((const float4*)sh.Kc)[t * 16 + jq];
        const float4 qv = ((const float4*)sh.Qc)[t * 16 + jq];
        float yp[4];
#pragma unroll
        for (int sI = 0; sI < 4; sI++) {
            fma4(S4[sI], sh.Vc[t * Hn + sI * 16 + rr], kv);
            yp[sI] = S4[sI].x * qv.x + S4[sI].y * qv.y + S4[sI].z * qv.z + S4[sI].w * qv.w;
        }
        float4* So = SBase + t * 1024;
#pragma unroll
        for (int sI = 0; sI < 4; sI++) So[sI * 256 + tid] = S4[sI];
#pragma unroll
        for (int sI = 0; sI < 4; sI++) {
            yp[sI] += __shfl_xor(yp[sI], 1);
            yp[sI] += __shfl_xor(yp[sI], 2);
            yp[sI] += __shfl_xor(yp[sI], 4);
            yp[sI] += __shfl_xor(yp[sI], 8);
        }
        if (jq == 0) {
#pragma unroll
            for (int sI = 0; sI < 4; sI++) sh.u.c.Yl[t * 68 + sI * 16 + rr] = yp[sI];
        }
    }
    __syncthreads();
    // FFN: thread = (token tg2, output quad cg2)
    const int tg2 = tid >> 4, cg2 = tid & 15;
    {
        float4 a = *(const float4*)&sh.u.c.Lb[0][cg2 * 4];
#pragma unroll 16
        for (int k = 0; k < 64; k++)
            fma4(a, sh.u.c.Yl[tg2 * 68 + k], *(const float4*)&sh.u.c.WT[0][k * 68 + cg2 * 4]);
        a.x = fmaxf(a.x, 0.f); a.y = fmaxf(a.y, 0.f);
        a.z = fmaxf(a.z, 0.f); a.w = fmaxf(a.w, 0.f);
        *(float4*)&sh.u.c.Y2[tg2 * 68 + cg2 * 4] = a;
    }
    __syncthreads();
    {
        float4 o = *(const float4*)&sh.u.c.Lb[1][cg2 * 4];
#pragma unroll 16
        for (int k = 0; k < 64; k++)
            fma4(o, sh.u.c.Y2[tg2 * 68 + k], *(const float4*)&sh.u.c.WT[1][k * 68 + cg2 * 4]);
        const float4 r4 = ((const float4*)sh.Rc)[tid];
        o.x = fmaxf(o.x, 0.f) + r4.x; o.y = fmaxf(o.y, 0.f) + r4.y;
        o.z = fmaxf(o.z, 0.f) + r4.z; o.w = fmaxf(o.w, 0.f) + r4.w;
        ((float4*)(outY + (size_t)(b * Tn + t0) * Hn))[tid] = o;
    }
}

extern "C" void kernel_launch(void* const* d_in, const int* in_sizes, int n_in,
                              void* d_out, int out_size, void* d_ws, size_t ws_size,
                              hipStream_t stream) {
    const float* x     = (const float*)d_in[0];
    const float* state = (const float*)d_in[1];
    const float* Wk    = (const float*)d_in[2];
    const float* Wq    = (const float*)d_in[3];
    const float* Wv    = (const float*)d_in[4];
    const float* gamma = (const float*)d_in[5];
    const float* beta  = (const float*)d_in[6];
    const float* W1    = (const float*)d_in[7];
    const float* b1    = (const float*)d_in[8];
    const float* W2    = (const float*)d_in[9];
    const float* b2    = (const float*)d_in[10];
    const float* Wsp   = (const float*)d_in[11];
    const float* bs    = (const float*)d_in[12];

    float* csum = (float*)d_ws;   // 8 * 64 * 4096 floats = 8 MB; scanned in place
    float* outY = (float*)d_out;
    float* outS = outY + (size_t)Bn * Tn * Hn;

    void* args[] = { (void*)&x, (void*)&state, (void*)&Wk, (void*)&Wq, (void*)&Wv,
                     (void*)&gamma, (void*)&beta, (void*)&W1, (void*)&b1, (void*)&W2,
                     (void*)&b2, (void*)&Wsp, (void*)&bs,
                     (void*)&csum, (void*)&outY, (void*)&outS };
    hipLaunchCooperativeKernel((const void*)fwp_fused, dim3(512), dim3(256), args, 0, stream);
}

// Round 5
// 193.874 us; speedup vs baseline: 2.2740x; 2.2740x over previous
//
#include <hip/hip_runtime.h>

#define Bn 8
#define Tn 1024
#define Fn 128
#define Hn 64
#define NC 32      // scan chunks per batch (32 tokens each)
#define CSZ 16     // tokens per k3 block

constexpr float EPS = 1e-5f;

__device__ __forceinline__ void fma4(float4& a, float s, const float4& w) {
    a.x = fmaf(s, w.x, a.x); a.y = fmaf(s, w.y, a.y);
    a.z = fmaf(s, w.z, a.z); a.w = fmaf(s, w.w, a.w);
}
__device__ __forceinline__ float4 f4zero() { return make_float4(0.f, 0.f, 0.f, 0.f); }

// ---------------- K1: LN + projections + relu + sumnorm + 32-token chunk kv-sum ----------------
// block: 32 tokens. GEMM [32x128]@[128x256] (K|Q|V|Ws). blockIdx = b*32 + c32.
__global__ __launch_bounds__(256) void k1_proj(
    const float* __restrict__ x, const float* __restrict__ gamma, const float* __restrict__ beta,
    const float* __restrict__ Wk, const float* __restrict__ Wq, const float* __restrict__ Wv,
    const float* __restrict__ Wsp, const float* __restrict__ bs,
    float* __restrict__ Kb, float* __restrict__ Qb, float* __restrict__ Vb, float* __restrict__ Rb,
    float* __restrict__ csum) {
    __shared__ float LW[32 * 260];   // [k in chunk][out 0..255]
    __shared__ float LX[32 * 36];    // [k in chunk][token 0..31]
    __shared__ float Kc[32 * Hn];    // normalized K for the block's 32 tokens
    __shared__ float Vc[32 * Hn];    // V
    const int tid  = threadIdx.x;
    const int tok0 = blockIdx.x * 32;
    const int tg   = tid >> 6;   // token group of 8 (also the wave index)
    const int cg   = tid & 63;   // output quad index (o = cg*4..cg*4+3)

    const float* WmS  = (tg == 0) ? Wk : (tg == 1) ? Wq : (tg == 2) ? Wv : Wsp;
    const float* wrow = WmS + (tid & 63) * Fn;

    // --- LayerNorm: thread owns token tt, features {c*32 + kk .. +3} for c=0..3 ---
    const int tt = tid >> 3, kk = (tid & 7) * 4;
    float4 xreg[4];
    float s = 0.f, ss = 0.f;
#pragma unroll
    for (int c = 0; c < 4; c++) {
        xreg[c] = *(const float4*)(x + (tok0 + tt) * Fn + c * 32 + kk);
        s  += xreg[c].x + xreg[c].y + xreg[c].z + xreg[c].w;
        ss += xreg[c].x * xreg[c].x + xreg[c].y * xreg[c].y
            + xreg[c].z * xreg[c].z + xreg[c].w * xreg[c].w;
    }
#pragma unroll
    for (int m = 1; m < 8; m <<= 1) { s += __shfl_xor(s, m); ss += __shfl_xor(ss, m); }
    const float mu = s * (1.f / Fn);
    const float rs = rsqrtf(ss * (1.f / Fn) - mu * mu + EPS);

    float4 acc[8];
#pragma unroll
    for (int i = 0; i < 8; i++) acc[i] = f4zero();

    for (int c = 0; c < 4; c++) {
        const int kc0 = c * 32;
#pragma unroll
        for (int r = 0; r < 8; r++) {
            const float4 wv = *(const float4*)(wrow + kc0 + r * 4);
            LW[(r * 4 + 0) * 260 + tid] = wv.x;
            LW[(r * 4 + 1) * 260 + tid] = wv.y;
            LW[(r * 4 + 2) * 260 + tid] = wv.z;
            LW[(r * 4 + 3) * 260 + tid] = wv.w;
        }
        {
            const float4 g4 = *(const float4*)(gamma + kc0 + kk);
            const float4 b4 = *(const float4*)(beta + kc0 + kk);
            const float4 xv = xreg[c];
            LX[(kk + 0) * 36 + tt] = (xv.x - mu) * rs * g4.x + b4.x;
            LX[(kk + 1) * 36 + tt] = (xv.y - mu) * rs * g4.y + b4.y;
            LX[(kk + 2) * 36 + tt] = (xv.z - mu) * rs * g4.z + b4.z;
            LX[(kk + 3) * 36 + tt] = (xv.w - mu) * rs * g4.w + b4.w;
        }
        __syncthreads();
#pragma unroll 8
        for (int kc = 0; kc < 32; kc++) {
            const float4 w4 = *(const float4*)&LW[kc * 260 + cg * 4];
            const float4 xa = *(const float4*)&LX[kc * 36 + tg * 8];
            const float4 xb = *(const float4*)&LX[kc * 36 + tg * 8 + 4];
            fma4(acc[0], xa.x, w4); fma4(acc[1], xa.y, w4);
            fma4(acc[2], xa.z, w4); fma4(acc[3], xa.w, w4);
            fma4(acc[4], xb.x, w4); fma4(acc[5], xb.y, w4);
            fma4(acc[6], xb.z, w4); fma4(acc[7], xb.w, w4);
        }
        __syncthreads();
    }

    // --- epilogue: relu (K,Q), sum-normalize (K,Q), +bs (R) ---
    const int m  = cg >> 4;               // 0=K 1=Q 2=V 3=R
    const int h0 = (cg & 15) * 4;
    if (m < 2) {
#pragma unroll
        for (int i = 0; i < 8; i++) {
            acc[i].x = fmaxf(acc[i].x, 0.f); acc[i].y = fmaxf(acc[i].y, 0.f);
            acc[i].z = fmaxf(acc[i].z, 0.f); acc[i].w = fmaxf(acc[i].w, 0.f);
        }
    }
    float rsum[8];
#pragma unroll
    for (int i = 0; i < 8; i++) {
        rsum[i] = acc[i].x + acc[i].y + acc[i].z + acc[i].w;
        rsum[i] += __shfl_xor(rsum[i], 1);
        rsum[i] += __shfl_xor(rsum[i], 2);
        rsum[i] += __shfl_xor(rsum[i], 4);
        rsum[i] += __shfl_xor(rsum[i], 8);
    }
    if (m < 2) {
#pragma unroll
        for (int i = 0; i < 8; i++) {
            const float inv = 1.f / (EPS + rsum[i]);
            acc[i].x *= inv; acc[i].y *= inv; acc[i].z *= inv; acc[i].w *= inv;
        }
    } else if (m == 3) {
        const float4 bv = *(const float4*)(bs + h0);
#pragma unroll
        for (int i = 0; i < 8; i++) {
            acc[i].x += bv.x; acc[i].y += bv.y; acc[i].z += bv.z; acc[i].w += bv.w;
        }
    }
    float* outp = (m == 0) ? Kb : (m == 1) ? Qb : (m == 2) ? Vb : Rb;
#pragma unroll
    for (int ti = 0; ti < 8; ti++)
        *(float4*)(outp + (tok0 + tg * 8 + ti) * Hn + h0) = acc[ti];
    if (m == 0) {
#pragma unroll
        for (int ti = 0; ti < 8; ti++) *(float4*)(Kc + (tg * 8 + ti) * Hn + h0) = acc[ti];
    } else if (m == 2) {
#pragma unroll
        for (int ti = 0; ti < 8; ti++) *(float4*)(Vc + (tg * 8 + ti) * Hn + h0) = acc[ti];
    }
    __syncthreads();

    // --- one 32-token chunk kv-sum -> csum[blockIdx] ---
    const int jq = tid & 15, rr = tid >> 4;
    float4 a4[4];
#pragma unroll
    for (int sI = 0; sI < 4; sI++) a4[sI] = f4zero();
    for (int t = 0; t < 32; t++) {
        const float4 kv = ((const float4*)Kc)[t * 16 + jq];
#pragma unroll
        for (int sI = 0; sI < 4; sI++) fma4(a4[sI], Vc[t * Hn + sI * 16 + rr], kv);
    }
    float4* out0 = (float4*)(csum + (size_t)blockIdx.x * 4096);
#pragma unroll
    for (int sI = 0; sI < 4; sI++) out0[sI * 256 + tid] = a4[sI];
}

// ---------------- K2: in-place exclusive scan over 32 chunks ----------------
__global__ __launch_bounds__(256) void k2_scan(const float* __restrict__ state,
                                               float* __restrict__ csum) {
    const int b = blockIdx.x >> 4, et = blockIdx.x & 15;
    const int e = et * 256 + threadIdx.x;
    float v[NC];
#pragma unroll
    for (int c = 0; c < NC; c++) v[c] = csum[(size_t)(b * NC + c) * 4096 + e];
    float acc = state[b * 4096 + e];
#pragma unroll
    for (int c = 0; c < NC; c++) {
        csum[(size_t)(b * NC + c) * 4096 + e] = acc;   // exclusive prefix (chunk start)
        acc += v[c];
    }
}

// ---------------- K3: replay 16-token half-chunk, stream S, y + FFN + residual ----------------
// blockIdx = b*64 + c16; scan-chunk = c16>>1; odd halves re-replay prev 16 tokens' kv.
__global__ __launch_bounds__(256, 2) void k3_main(
    const float* __restrict__ Kb, const float* __restrict__ Qb, const float* __restrict__ Vb,
    const float* __restrict__ cstart, const float* __restrict__ Rb,
    const float* __restrict__ W1, const float* __restrict__ b1,
    const float* __restrict__ W2, const float* __restrict__ b2,
    float* __restrict__ outY, float* __restrict__ outS) {
    __shared__ float Kc[CSZ * Hn];
    __shared__ float Qc[CSZ * Hn];
    __shared__ float Vc[CSZ * Hn];
    __shared__ float Kp[CSZ * Hn];     // previous half-chunk K (odd blocks)
    __shared__ float Vp[CSZ * Hn];
    __shared__ float WT[2][64 * 68];   // transposed [k][h]
    __shared__ float Yl[CSZ * 68];
    __shared__ float Y2[CSZ * 68];
    __shared__ float Lb[2][64];
    const int tid = threadIdx.x;
    const int bl  = blockIdx.x;
    const int b = bl >> 6, c16 = bl & 63;
    const int t0 = c16 * CSZ;
    const int odd = bl & 1;
    // stage K,Q,V (16 tok x 64 = 256 float4 each)
    ((float4*)Kc)[tid] = ((const float4*)(Kb + (b * Tn + t0) * Hn))[tid];
    ((float4*)Qc)[tid] = ((const float4*)(Qb + (b * Tn + t0) * Hn))[tid];
    ((float4*)Vc)[tid] = ((const float4*)(Vb + (b * Tn + t0) * Hn))[tid];
    if (odd) {
        ((float4*)Kp)[tid] = ((const float4*)(Kb + (b * Tn + t0 - CSZ) * Hn))[tid];
        ((float4*)Vp)[tid] = ((const float4*)(Vb + (b * Tn + t0 - CSZ) * Hn))[tid];
    }
    // stage W1,W2 transposed: 1024 float4 each -> 4 rounds of 256
#pragma unroll
    for (int mat = 0; mat < 2; mat++) {
        const float4* Wg = (const float4*)(mat ? W2 : W1);
#pragma unroll
        for (int r = 0; r < 4; r++) {
            const int f4i = tid + 256 * r;
            const float4 wv = Wg[f4i];
            const int h = f4i >> 4;
            const int k = (f4i & 15) * 4;
            WT[mat][(k + 0) * 68 + h] = wv.x;
            WT[mat][(k + 1) * 68 + h] = wv.y;
            WT[mat][(k + 2) * 68 + h] = wv.z;
            WT[mat][(k + 3) * 68 + h] = wv.w;
        }
    }
    if (tid < 64) Lb[0][tid] = b1[tid];
    else if (tid < 128) Lb[1][tid - 64] = b2[tid - 64];
    // chunk-start state (shared by the two half-chunks: index bl>>1)
    float4 S4[4];
    const float4* cs = (const float4*)(cstart + (size_t)(bl >> 1) * 4096);
#pragma unroll
    for (int sI = 0; sI < 4; sI++) S4[sI] = cs[sI * 256 + tid];
    __syncthreads();

    const int jq = tid & 15, rr = tid >> 4;
    // odd half: advance S over the previous 16 tokens (no stores)
    if (odd) {
        for (int t = 0; t < CSZ; t++) {
            const float4 kv = ((const float4*)Kp)[t * 16 + jq];
#pragma unroll
            for (int sI = 0; sI < 4; sI++) fma4(S4[sI], Vp[t * Hn + sI * 16 + rr], kv);
        }
    }
    float4* SBase = (float4*)outS + (size_t)(b * Tn + t0) * 1024;
    for (int t = 0; t < CSZ; t++) {
        const float4 kv = ((const float4*)Kc)[t * 16 + jq];
        const float4 qv = ((const float4*)Qc)[t * 16 + jq];
        float yp[4];
#pragma unroll
        for (int sI = 0; sI < 4; sI++) {
            fma4(S4[sI], Vc[t * Hn + sI * 16 + rr], kv);
            yp[sI] = S4[sI].x * qv.x + S4[sI].y * qv.y + S4[sI].z * qv.z + S4[sI].w * qv.w;
        }
        float4* So = SBase + t * 1024;
#pragma unroll
        for (int sI = 0; sI < 4; sI++) So[sI * 256 + tid] = S4[sI];
#pragma unroll
        for (int sI = 0; sI < 4; sI++) {
            yp[sI] += __shfl_xor(yp[sI], 1);
            yp[sI] += __shfl_xor(yp[sI], 2);
            yp[sI] += __shfl_xor(yp[sI], 4);
            yp[sI] += __shfl_xor(yp[sI], 8);
        }
        if (jq == 0) {
#pragma unroll
            for (int sI = 0; sI < 4; sI++) Yl[t * 68 + sI * 16 + rr] = yp[sI];
        }
    }
    __syncthreads();

    // --- FFN: thread = (token tg, output quad cg) ---
    const int tg = tid >> 4, cg = tid & 15;
    float4 a = *(const float4*)&Lb[0][cg * 4];
#pragma unroll 16
    for (int k = 0; k < 64; k++)
        fma4(a, Yl[tg * 68 + k], *(const float4*)&WT[0][k * 68 + cg * 4]);
    a.x = fmaxf(a.x, 0.f); a.y = fmaxf(a.y, 0.f); a.z = fmaxf(a.z, 0.f); a.w = fmaxf(a.w, 0.f);
    *(float4*)&Y2[tg * 68 + cg * 4] = a;
    __syncthreads();
    float4 o = *(const float4*)&Lb[1][cg * 4];
#pragma unroll 16
    for (int k = 0; k < 64; k++)
        fma4(o, Y2[tg * 68 + k], *(const float4*)&WT[1][k * 68 + cg * 4]);
    const float4 r4 = ((const float4*)(Rb + (b * Tn + t0) * Hn))[tid];
    o.x = fmaxf(o.x, 0.f) + r4.x; o.y = fmaxf(o.y, 0.f) + r4.y;
    o.z = fmaxf(o.z, 0.f) + r4.z; o.w = fmaxf(o.w, 0.f) + r4.w;
    ((float4*)(outY + (b * Tn + t0) * Hn))[tid] = o;
}

extern "C" void kernel_launch(void* const* d_in, const int* in_sizes, int n_in,
                              void* d_out, int out_size, void* d_ws, size_t ws_size,
                              hipStream_t stream) {
    const float* x     = (const float*)d_in[0];
    const float* state = (const float*)d_in[1];
    const float* Wk    = (const float*)d_in[2];
    const float* Wq    = (const float*)d_in[3];
    const float* Wv    = (const float*)d_in[4];
    const float* gamma = (const float*)d_in[5];
    const float* beta  = (const float*)d_in[6];
    const float* W1    = (const float*)d_in[7];
    const float* b1    = (const float*)d_in[8];
    const float* W2    = (const float*)d_in[9];
    const float* b2    = (const float*)d_in[10];
    const float* Wsp   = (const float*)d_in[11];
    const float* bs    = (const float*)d_in[12];

    float* ws   = (float*)d_ws;
    float* Kb   = ws;                 // 524288 floats (2 MB)
    float* Qb   = ws + 524288;
    float* Vb   = ws + 1048576;
    float* Rb   = ws + 1572864;
    float* csum = ws + 2097152;       // 8*32*4096 floats (4 MB); scanned in-place

    float* outY = (float*)d_out;
    float* outS = outY + (size_t)Bn * Tn * Hn;

    k1_proj<<<256, 256, 0, stream>>>(x, gamma, beta, Wk, Wq, Wv, Wsp, bs, Kb, Qb, Vb, Rb, csum);
    k2_scan<<<128, 256, 0, stream>>>(state, csum);
    k3_main<<<512, 256, 0, stream>>>(Kb, Qb, Vb, csum, Rb, W1, b1, W2, b2, outY, outS);
}